// Round 5
// baseline (136.267 us; speedup 1.0000x reference)
//
#include <hip/hip_runtime.h>

#define NN 2048
#define NH 4
#define DD 64
#define FIN 128
#define NB 4
#define LOG2E 1.44269504f

typedef unsigned short u16;
typedef unsigned int u32;
typedef short sh8 __attribute__((ext_vector_type(8)));
typedef float f32x4 __attribute__((ext_vector_type(4)));

static __device__ __forceinline__ u16 f2bf(float f) {   // RNE
    u32 u = __builtin_bit_cast(u32, f);
    u += 0x7fffu + ((u >> 16) & 1u);
    return (u16)(u >> 16);
}
static __device__ __forceinline__ u32 pk_bf(float a, float b) {
    u32 ua = __builtin_bit_cast(u32, a) + 0x8000u;
    u32 ub = __builtin_bit_cast(u32, b) + 0x8000u;
    return __builtin_amdgcn_perm(ub, ua, 0x07060302u);
}
// gfx950 packed f32->bf16 convert (RNE). lo = a, hi = b. No builtin; inline asm.
static __device__ __forceinline__ u32 cvt_pk(float a, float b) {
    u32 r;
    asm("v_cvt_pk_bf16_f32 %0, %1, %2" : "=v"(r) : "v"(a), "v"(b));
    return r;
}
static __device__ __forceinline__ float fast_exp2(float x) {
    float r;
    asm("v_exp_f32 %0, %1" : "=v"(r) : "v"(x));
    return r;
}

// ---- runtime C/D layout probe (load-bearing since R4) ----
static __device__ __forceinline__ void cd_probe(int ln15, int q, int* irow, int* icol) {
    sh8 pa, pb, qa, qb;
    #pragma unroll
    for (int ii = 0; ii < 8; ++ii) {
        pa[ii] = (short)f2bf((float)ln15);   // A[m][k] = m
        pb[ii] = 0;
        qa[ii] = 0;
        qb[ii] = (short)f2bf((float)ln15);   // B[k][n] = n
    }
    if (q == 0) { pb[0] = (short)f2bf(1.0f); qa[0] = (short)f2bf(1.0f); }
    f32x4 z = {};
    f32x4 prow = __builtin_amdgcn_mfma_f32_16x16x32_bf16(pa, pb, z, 0, 0, 0);
    f32x4 pcol = __builtin_amdgcn_mfma_f32_16x16x32_bf16(qa, qb, z, 0, 0, 0);
    #pragma unroll
    for (int r = 0; r < 4; ++r) {
        irow[r] = (int)(prow[r] + 0.5f);
        icol[r] = (int)(pcol[r] + 0.5f);
    }
}

// ws layout (bytes):
//   WT   [256][128] bf16 @ 0        : 65536
//   ei   [B][H][N]  f32  @ 65536    : 131072   (log2e-scaled)
//   ej   [B][H][N]  f32  @ 196608   : 131072   (log2e-scaled)
//   hTf  fragment-major  @ 327680   : 4194304  ([b][hd][jt64][dt4][lane64][8] bf16)
//   l_p  @ 6619136 : 131072*js  (js<=4)
//   o_p  @ 7143424 : 8388608*js (js<=4)

// W -> WT (transposed bf16). 32 blocks; adj packing lives in k_attn's prologue.
__global__ __launch_bounds__(256)
void k_prep(const float* __restrict__ W, u16* __restrict__ WT) {
    const int bt  = blockIdx.x;          // 0..31
    const int kt  = bt & 3;
    const int ct8 = bt >> 2;
    __shared__ float tile[32][33];
    const int tid = threadIdx.x;
    const int rr = tid >> 5, cc = tid & 31;
    #pragma unroll
    for (int i = 0; i < 4; ++i)
        tile[rr + 8 * i][cc] = W[(size_t)(kt * 32 + rr + 8 * i) * 256 + ct8 * 32 + cc];
    __syncthreads();
    #pragma unroll
    for (int i = 0; i < 4; ++i)
        WT[(size_t)(ct8 * 32 + rr + 8 * i) * FIN + kt * 32 + cc] = f2bf(tile[cc][rr + 8 * i]);
}

// h = x@W in MFMA fragment-major layout + ei/ej (log2e-scaled). grid (nb=32, b=4), wave=head.
__global__ __launch_bounds__(256)
void k_gemm_h(const float* __restrict__ x, const u16* __restrict__ WT,
              const float* __restrict__ a,
              u16* __restrict__ hTf, float* __restrict__ ei_g, float* __restrict__ ej_g) {
    const int nb = blockIdx.x, b = blockIdx.y;
    const int tid = threadIdx.x, hd = tid >> 6, lane = tid & 63, ln15 = lane & 15, q = lane >> 4;
    const int q8 = q * 8;
    const int n0 = nb * 64;

    __shared__ u16 xs[64][136];
    __shared__ float cs[NH][4][16][20];   // [hd][nt][row][col+pad], reused per ct (same-wave)
    {
        const int col = (tid & 31) * 4;
        const int r0  = tid >> 5;
        #pragma unroll
        for (int rr = 0; rr < 8; ++rr) {
            const int row = r0 + rr * 8;
            const float4 v = *(const float4*)(x + ((size_t)(b * NN + n0 + row)) * FIN + col);
            *(u32*)&xs[row][col]     = pk_bf(v.x, v.y);
            *(u32*)&xs[row][col + 2] = pk_bf(v.z, v.w);
        }
    }
    __syncthreads();

    int irow[4], icol[4];
    cd_probe(ln15, q, irow, icol);

    f32x4 acc[4][4] = {};                // [ct][nt]
    #pragma unroll
    for (int ks = 0; ks < 4; ++ks) {
        sh8 af[4], bfr[4];
        #pragma unroll
        for (int ct = 0; ct < 4; ++ct)
            af[ct] = *(const sh8*)(WT + (size_t)(hd * 64 + ct * 16 + ln15) * FIN + ks * 32 + q8);
        #pragma unroll
        for (int nt = 0; nt < 4; ++nt)
            bfr[nt] = *(const sh8*)&xs[nt * 16 + ln15][ks * 32 + q8];
        #pragma unroll
        for (int ct = 0; ct < 4; ++ct)
            #pragma unroll
            for (int nt = 0; nt < 4; ++nt)
                acc[ct][nt] = __builtin_amdgcn_mfma_f32_16x16x32_bf16(af[ct], bfr[nt], acc[ct][nt], 0, 0, 0);
    }

    float eip[4] = {}, ejq[4] = {};
    #pragma unroll
    for (int ct = 0; ct < 4; ++ct) {
        // canonicalize this ct through LDS (same-wave: no barrier needed)
        #pragma unroll
        for (int nt = 0; nt < 4; ++nt)
            #pragma unroll
            for (int r = 0; r < 4; ++r)
                cs[hd][nt][irow[r]][icol[r]] = acc[ct][nt][r];

        // fragment-major hTf write: lane (ln15,q) holds d=ct*16+ln15, j=n0+p*32+q*8+i
        #pragma unroll
        for (int p = 0; p < 2; ++p) {
            const float4 c0 = *(const float4*)&cs[hd][2 * p + (q >> 1)][ln15][(q & 1) * 8];
            const float4 c1 = *(const float4*)&cs[hd][2 * p + (q >> 1)][ln15][(q & 1) * 8 + 4];
            uint4 o;
            o.x = pk_bf(c0.x, c0.y); o.y = pk_bf(c0.z, c0.w);
            o.z = pk_bf(c1.x, c1.y); o.w = pk_bf(c1.z, c1.w);
            *(uint4*)(hTf + ((((size_t)(b * NH + hd) * 64 + nb * 2 + p) * 4 + ct) * 512) + lane * 8) = o;
        }

        // ei/ej partial sums (canonical reads)
        float a1v[4], a2v[4];
        #pragma unroll
        for (int r = 0; r < 4; ++r) {
            const int d = ct * 16 + 4 * q + r;
            a1v[r] = a[d] * LOG2E;
            a2v[r] = a[64 + d] * LOG2E;
        }
        #pragma unroll
        for (int nt = 0; nt < 4; ++nt)
            #pragma unroll
            for (int r = 0; r < 4; ++r) {
                const float v = cs[hd][nt][4 * q + r][ln15];
                eip[nt] += v * a1v[r];
                ejq[nt] += v * a2v[r];
            }
    }
    #pragma unroll
    for (int nt = 0; nt < 4; ++nt) {
        eip[nt] += __shfl_xor(eip[nt], 16);
        eip[nt] += __shfl_xor(eip[nt], 32);
        ejq[nt] += __shfl_xor(ejq[nt], 16);
        ejq[nt] += __shfl_xor(ejq[nt], 32);
    }
    if (lane < 16) {
        const size_t bhd = (size_t)(b * NH + hd) * NN;
        #pragma unroll
        for (int nt = 0; nt < 4; ++nt) {
            ei_g[bhd + n0 + nt * 16 + lane] = eip[nt];
            ej_g[bhd + n0 + nt * 16 + lane] = ejq[nt];
        }
    }
}

// grid (ib=64, js, b=4), block 256 (wave = head).
// Prologue: adj slice -> LDS bitmask; ej slice -> LDS (per head).
// Main loop: software-pipelined — av fragments for step t+1 are computed BEFORE
// the MFMAs of step t issue, so the exp chain and matrix pipe overlap.
template <int NJT>
__global__ __launch_bounds__(256, 4)
void k_attn(const int* __restrict__ adj, const u16* __restrict__ hTf,
            const float* __restrict__ ei_g, const float* __restrict__ ej_g,
            float* __restrict__ o_part, float* __restrict__ l_part) {
    const int ib = blockIdx.x, js = blockIdx.y, b = blockIdx.z;
    const int js_n = gridDim.y;
    const int tid = threadIdx.x, hd = tid >> 6, lane = tid & 63, ln15 = lane & 15, q = lane >> 4;
    const int q8 = q * 8;
    const int iA = ib * 32 + ln15;
    const int jt0 = js * NJT;

    __shared__ u32 mlds[32][NJT + 1];       // odd stride: conflict-free column reads
    __shared__ float ejs[NH][NJT * 32];     // per-head ej slice (log2e-scaled)

    // ---- prologue A: adj -> bitmask in LDS (nibble + shfl-OR, 8-deep load batches) ----
    {
        const int row = (hd << 3) + (lane >> 3);                   // 0..31, 8 rows per wave
        const int* abase = adj + (size_t)(b * NN + ib * 32 + row) * NN + jt0 * 32 + (lane & 7) * 4;
        #pragma unroll
        for (int jb = 0; jb < NJT; jb += 8) {
            int4 vv[8];
            #pragma unroll
            for (int u = 0; u < 8; ++u)
                vv[u] = *(const int4*)(abase + (jb + u) * 32);
            #pragma unroll
            for (int u = 0; u < 8; ++u) {
                u32 nib = (vv[u].x ? 1u : 0u) | (vv[u].y ? 2u : 0u) |
                          (vv[u].z ? 4u : 0u) | (vv[u].w ? 8u : 0u);
                u32 w = nib << (4 * (lane & 7));
                w |= __shfl_xor(w, 1);
                w |= __shfl_xor(w, 2);
                w |= __shfl_xor(w, 4);
                if ((lane & 7) == 0) mlds[row][jb + u] = w;
            }
        }
    }
    const size_t bhd = (size_t)(b * NH + hd) * NN;
    // ---- prologue B: ej slice -> LDS (each wave stages its own head's slice) ----
    {
        const float* src = ej_g + bhd + jt0 * 32;
        #pragma unroll
        for (int u = 0; u < NJT / 8; ++u) {
            const int o4 = (u * 64 + lane) * 4;
            *(float4*)&ejs[hd][o4] = *(const float4*)(src + o4);
        }
    }
    __syncthreads();

    int irow[4], icol[4];
    cd_probe(ln15, q, irow, icol);

    const float eivA = ei_g[bhd + iA];
    const float eivB = ei_g[bhd + iA + 16];
    const u16*  hfp  = hTf + (size_t)(b * NH + hd) * (64 * 2048) + (size_t)lane * 8;

    sh8 ones;
    #pragma unroll
    for (int ii = 0; ii < 8; ++ii) ones[ii] = (short)0x3F80;

    f32x4 acc[8] = {};
    f32x4 accl[2] = {};

    // e-chain for one step -> packed bf16 fragments (mask applied)
    auto COMPUTE = [&](int t, uint4& oA, uint4& oB) {
        const u32 mA = mlds[ln15][t];
        const u32 mB = mlds[ln15 + 16][t];
        const float4 e0 = *(const float4*)&ejs[hd][t * 32 + q8];
        const float4 e1 = *(const float4*)&ejs[hd][t * 32 + q8 + 4];
        const float ef[8] = { e0.x, e0.y, e0.z, e0.w, e1.x, e1.y, e1.z, e1.w };
        const u32 mqA = mA >> q8;
        const u32 mqB = mB >> q8;
        float pA[8], pB[8];
        #pragma unroll
        for (int ii = 0; ii < 8; ++ii) {
            float eA = eivA + ef[ii];
            float eB = eivB + ef[ii];
            eA = fmaxf(eA, 0.2f * eA);
            eB = fmaxf(eB, 0.2f * eB);
            const float xA = fast_exp2(eA);
            const float xB = fast_exp2(eB);
            pA[ii] = (mqA & (1u << ii)) ? xA : 0.f;
            pB[ii] = (mqB & (1u << ii)) ? xB : 0.f;
        }
        oA.x = cvt_pk(pA[0], pA[1]); oA.y = cvt_pk(pA[2], pA[3]);
        oA.z = cvt_pk(pA[4], pA[5]); oA.w = cvt_pk(pA[6], pA[7]);
        oB.x = cvt_pk(pB[0], pB[1]); oB.y = cvt_pk(pB[2], pB[3]);
        oB.z = cvt_pk(pB[4], pB[5]); oB.w = cvt_pk(pB[6], pB[7]);
    };

    sh8 H[2][4];
    #pragma unroll
    for (int s = 0; s < 2; ++s)
        #pragma unroll
        for (int k = 0; k < 4; ++k)
            H[s][k] = *(const sh8*)(hfp + (size_t)(jt0 + s) * 2048 + k * 512);

    uint4 avAc, avBc, avAn, avBn;
    COMPUTE(0, avAc, avBc);

    #pragma unroll
    for (int t = 0; t < NJT; ++t) {
        // next step's e-chain first: MFMAs below have no dependence on it
        if (t + 1 < NJT) COMPUTE(t + 1, avAn, avBn);

        const sh8 av = __builtin_bit_cast(sh8, avAc);
        const sh8 bv = __builtin_bit_cast(sh8, avBc);
        acc[0] = __builtin_amdgcn_mfma_f32_16x16x32_bf16(av, H[t & 1][0], acc[0], 0, 0, 0);
        acc[1] = __builtin_amdgcn_mfma_f32_16x16x32_bf16(av, H[t & 1][1], acc[1], 0, 0, 0);
        acc[2] = __builtin_amdgcn_mfma_f32_16x16x32_bf16(av, H[t & 1][2], acc[2], 0, 0, 0);
        acc[3] = __builtin_amdgcn_mfma_f32_16x16x32_bf16(av, H[t & 1][3], acc[3], 0, 0, 0);
        accl[0] = __builtin_amdgcn_mfma_f32_16x16x32_bf16(av, ones, accl[0], 0, 0, 0);
        acc[4] = __builtin_amdgcn_mfma_f32_16x16x32_bf16(bv, H[t & 1][0], acc[4], 0, 0, 0);
        acc[5] = __builtin_amdgcn_mfma_f32_16x16x32_bf16(bv, H[t & 1][1], acc[5], 0, 0, 0);
        acc[6] = __builtin_amdgcn_mfma_f32_16x16x32_bf16(bv, H[t & 1][2], acc[6], 0, 0, 0);
        acc[7] = __builtin_amdgcn_mfma_f32_16x16x32_bf16(bv, H[t & 1][3], acc[7], 0, 0, 0);
        accl[1] = __builtin_amdgcn_mfma_f32_16x16x32_bf16(bv, ones, accl[1], 0, 0, 0);

        if (t + 2 < NJT) {
            #pragma unroll
            for (int k = 0; k < 4; ++k)
                H[t & 1][k] = *(const sh8*)(hfp + (size_t)(jt0 + t + 2) * 2048 + k * 512);
        }
        if (t + 1 < NJT) { avAc = avAn; avBc = avBn; }
    }

    const size_t pbA = (((size_t)b * 128 + ib * 2 + 0) * js_n + js) * NH + hd;
    const size_t pbB = (((size_t)b * 128 + ib * 2 + 1) * js_n + js) * NH + hd;
    #pragma unroll
    for (int r = 0; r < 4; ++r) {
        l_part[pbA * 16 + irow[r]] = accl[0][r];
        l_part[pbB * 16 + irow[r]] = accl[1][r];
    }
    float* opA = o_part + pbA * 1024;
    float* opB = o_part + pbB * 1024;
    #pragma unroll
    for (int dt = 0; dt < 4; ++dt)
        #pragma unroll
        for (int r = 0; r < 4; ++r) {
            opA[(size_t)irow[r] * 64 + dt * 16 + icol[r]] = acc[dt][r];
            opB[(size_t)irow[r] * 64 + dt * 16 + icol[r]] = acc[4 + dt][r];
        }
}

// accumulate-form combine (register-light)
template <int JS>
__global__ __launch_bounds__(256)
void k_combine(const float* __restrict__ o_part, const float* __restrict__ l_part,
               float* __restrict__ out) {
    const int ib = blockIdx.x, b = blockIdx.y;
    const int tid = threadIdx.x;
    const int i = tid >> 4, d4 = (tid & 15) * 4;
    float4 sacc = {0.f, 0.f, 0.f, 0.f};
    #pragma unroll
    for (int h = 0; h < NH; ++h) {
        float l = 0.f;
        float4 oh = {0.f, 0.f, 0.f, 0.f};
        #pragma unroll
        for (int js = 0; js < JS; ++js) {
            const size_t pbase = (((size_t)b * 128 + ib) * JS + js) * NH + h;
            l += l_part[pbase * 16 + i];
            const float4 ov = *(const float4*)(o_part + pbase * 1024 + (size_t)i * 64 + d4);
            oh.x += ov.x; oh.y += ov.y; oh.z += ov.z; oh.w += ov.w;
        }
        const float inv = 0.25f / l;
        sacc.x += oh.x * inv; sacc.y += oh.y * inv;
        sacc.z += oh.z * inv; sacc.w += oh.w * inv;
    }
    *(float4*)(out + ((size_t)(b * NN) + ib * 16 + i) * DD + d4) = sacc;
}

extern "C" void kernel_launch(void* const* d_in, const int* in_sizes, int n_in,
                              void* d_out, int out_size, void* d_ws, size_t ws_size,
                              hipStream_t stream) {
    const float* x = nullptr; const int* adj = nullptr;
    const float* W = nullptr; const float* a = nullptr;
    for (int i = 0; i < n_in; ++i) {
        switch (in_sizes[i]) {
            case NB * NN * FIN:  x   = (const float*)d_in[i]; break;
            case NB * NN * NN:   adj = (const int*)d_in[i];   break;
            case FIN * 256:      W   = (const float*)d_in[i]; break;
            case 2 * DD:         a   = (const float*)d_in[i]; break;
            default: break;
        }
    }
    if (!x)   x   = (const float*)d_in[0];
    if (!adj) adj = (const int*)d_in[1];
    if (!W)   W   = (const float*)d_in[2];
    if (!a)   a   = (const float*)d_in[3];
    float* out = (float*)d_out;

    char* ws = (char*)d_ws;
    u16*   WT  = (u16*)(ws);
    float* ei  = (float*)(ws + 65536);
    float* ej  = (float*)(ws + 196608);
    u16*   hTf = (u16*)(ws + 327680);
    float* l_p = (float*)(ws + 6619136);
    float* o_p = (float*)(ws + 7143424);

    const size_t need4 = 7143424 + (size_t)4 * 8388608;
    const size_t need2 = 7143424 + (size_t)2 * 8388608;
    const int js_n = (ws_size >= need4) ? 4 : (ws_size >= need2) ? 2 : 1;

    k_prep<<<dim3(32), dim3(256), 0, stream>>>(W, WT);
    k_gemm_h<<<dim3(32, NB), dim3(256), 0, stream>>>(x, WT, a, hTf, ei, ej);
    if (js_n == 4)
        k_attn<16><<<dim3(64, 4, NB), dim3(256), 0, stream>>>(adj, hTf, ei, ej, o_p, l_p);
    else if (js_n == 2)
        k_attn<32><<<dim3(64, 2, NB), dim3(256), 0, stream>>>(adj, hTf, ei, ej, o_p, l_p);
    else
        k_attn<64><<<dim3(64, 1, NB), dim3(256), 0, stream>>>(adj, hTf, ei, ej, o_p, l_p);
    if (js_n == 4)      k_combine<4><<<dim3(128, NB), dim3(256), 0, stream>>>(o_p, l_p, out);
    else if (js_n == 2) k_combine<2><<<dim3(128, NB), dim3(256), 0, stream>>>(o_p, l_p, out);
    else                k_combine<1><<<dim3(128, NB), dim3(256), 0, stream>>>(o_p, l_p, out);
}

// Round 7
// 134.628 us; speedup vs baseline: 1.0122x; 1.0122x over previous
//
#include <hip/hip_runtime.h>

#define NN 2048
#define NH 4
#define DD 64
#define FIN 128
#define NB 4
#define LOG2E 1.44269504f

typedef unsigned short u16;
typedef unsigned int u32;
typedef short sh8 __attribute__((ext_vector_type(8)));
typedef float f32x4 __attribute__((ext_vector_type(4)));

static __device__ __forceinline__ u16 f2bf(float f) {   // RNE
    u32 u = __builtin_bit_cast(u32, f);
    u += 0x7fffu + ((u >> 16) & 1u);
    return (u16)(u >> 16);
}
static __device__ __forceinline__ u32 pk_bf(float a, float b) {
    u32 ua = __builtin_bit_cast(u32, a) + 0x8000u;
    u32 ub = __builtin_bit_cast(u32, b) + 0x8000u;
    return __builtin_amdgcn_perm(ub, ua, 0x07060302u);
}
// gfx950 packed f32->bf16 convert (RNE). Low word = a, high word = b.
static __device__ __forceinline__ u32 cvt_pk(float a, float b) {
    u32 r;
    asm("v_cvt_pk_bf16_f32 %0, %1, %2" : "=v"(r) : "v"(a), "v"(b));
    return r;
}
static __device__ __forceinline__ float fast_exp2(float x) {
    float r;
    asm("v_exp_f32 %0, %1" : "=v"(r) : "v"(x));
    return r;
}

// ---- runtime C/D layout probe (load-bearing since R4) ----
static __device__ __forceinline__ void cd_probe(int ln15, int q, int* irow, int* icol) {
    sh8 pa, pb, qa, qb;
    #pragma unroll
    for (int ii = 0; ii < 8; ++ii) {
        pa[ii] = (short)f2bf((float)ln15);   // A[m][k] = m
        pb[ii] = 0;
        qa[ii] = 0;
        qb[ii] = (short)f2bf((float)ln15);   // B[k][n] = n
    }
    if (q == 0) { pb[0] = (short)f2bf(1.0f); qa[0] = (short)f2bf(1.0f); }
    f32x4 z = {};
    f32x4 prow = __builtin_amdgcn_mfma_f32_16x16x32_bf16(pa, pb, z, 0, 0, 0);
    f32x4 pcol = __builtin_amdgcn_mfma_f32_16x16x32_bf16(qa, qb, z, 0, 0, 0);
    #pragma unroll
    for (int r = 0; r < 4; ++r) {
        irow[r] = (int)(prow[r] + 0.5f);
        icol[r] = (int)(pcol[r] + 0.5f);
    }
}

// ws layout (bytes):
//   WT   [256][128] bf16 @ 0        : 65536
//   Ea   [B][H][N] f32  @ 65536     : 131072   exp2(l2e*ei)
//   Ga   [B][H][N] f32  @ 196608    : 131072   exp2(0.2*l2e*ei)
//   Fb   [B][H][N] f32  @ 327680    : 131072   exp2(l2e*ej)
//   Hb   [B][H][N] f32  @ 458752    : 131072   exp2(0.2*l2e*ej)
//   hTf  fragment-major @ 589824    : 4194304  ([b][hd][jt64][dt4][lane64][8] bf16)
//   l_p  @ 4784128 : 131072*js  (js<=4)
//   o_p  @ 5308416 : 8388608*js (js<=4)

// W -> WT (transposed bf16). 32 blocks; adj packing lives in k_attn's prologue.
__global__ __launch_bounds__(256)
void k_prep(const float* __restrict__ W, u16* __restrict__ WT) {
    const int bt  = blockIdx.x;          // 0..31
    const int kt  = bt & 3;
    const int ct8 = bt >> 2;
    __shared__ float tile[32][33];
    const int tid = threadIdx.x;
    const int rr = tid >> 5, cc = tid & 31;
    #pragma unroll
    for (int i = 0; i < 4; ++i)
        tile[rr + 8 * i][cc] = W[(size_t)(kt * 32 + rr + 8 * i) * 256 + ct8 * 32 + cc];
    __syncthreads();
    #pragma unroll
    for (int i = 0; i < 4; ++i)
        WT[(size_t)(ct8 * 32 + rr + 8 * i) * FIN + kt * 32 + cc] = f2bf(tile[cc][rr + 8 * i]);
}

// h = x@W in MFMA fragment-major layout + exp-factor arrays. grid (nb=32, b=4), wave=head.
__global__ __launch_bounds__(256)
void k_gemm_h(const float* __restrict__ x, const u16* __restrict__ WT,
              const float* __restrict__ a,
              u16* __restrict__ hTf, float* __restrict__ Ea_g, float* __restrict__ Ga_g,
              float* __restrict__ Fb_g, float* __restrict__ Hb_g) {
    const int nb = blockIdx.x, b = blockIdx.y;
    const int tid = threadIdx.x, hd = tid >> 6, lane = tid & 63, ln15 = lane & 15, q = lane >> 4;
    const int q8 = q * 8;
    const int n0 = nb * 64;

    __shared__ u16 xs[64][136];
    __shared__ float cs[NH][4][16][20];   // [hd][nt][row][col+pad], reused per ct (same-wave)
    {
        const int col = (tid & 31) * 4;
        const int r0  = tid >> 5;
        #pragma unroll
        for (int rr = 0; rr < 8; ++rr) {
            const int row = r0 + rr * 8;
            const float4 v = *(const float4*)(x + ((size_t)(b * NN + n0 + row)) * FIN + col);
            *(u32*)&xs[row][col]     = pk_bf(v.x, v.y);
            *(u32*)&xs[row][col + 2] = pk_bf(v.z, v.w);
        }
    }
    __syncthreads();

    int irow[4], icol[4];
    cd_probe(ln15, q, irow, icol);

    f32x4 acc[4][4] = {};                // [ct][nt]
    #pragma unroll
    for (int ks = 0; ks < 4; ++ks) {
        sh8 af[4], bfr[4];
        #pragma unroll
        for (int ct = 0; ct < 4; ++ct)
            af[ct] = *(const sh8*)(WT + (size_t)(hd * 64 + ct * 16 + ln15) * FIN + ks * 32 + q8);
        #pragma unroll
        for (int nt = 0; nt < 4; ++nt)
            bfr[nt] = *(const sh8*)&xs[nt * 16 + ln15][ks * 32 + q8];
        #pragma unroll
        for (int ct = 0; ct < 4; ++ct)
            #pragma unroll
            for (int nt = 0; nt < 4; ++nt)
                acc[ct][nt] = __builtin_amdgcn_mfma_f32_16x16x32_bf16(af[ct], bfr[nt], acc[ct][nt], 0, 0, 0);
    }

    float eip[4] = {}, ejq[4] = {};
    #pragma unroll
    for (int ct = 0; ct < 4; ++ct) {
        // canonicalize this ct through LDS (same-wave: no barrier needed)
        #pragma unroll
        for (int nt = 0; nt < 4; ++nt)
            #pragma unroll
            for (int r = 0; r < 4; ++r)
                cs[hd][nt][irow[r]][icol[r]] = acc[ct][nt][r];

        // fragment-major hTf write: lane (ln15,q) holds d=ct*16+ln15, j=n0+p*32+q*8+i
        #pragma unroll
        for (int p = 0; p < 2; ++p) {
            const float4 c0 = *(const float4*)&cs[hd][2 * p + (q >> 1)][ln15][(q & 1) * 8];
            const float4 c1 = *(const float4*)&cs[hd][2 * p + (q >> 1)][ln15][(q & 1) * 8 + 4];
            uint4 o;
            o.x = pk_bf(c0.x, c0.y); o.y = pk_bf(c0.z, c0.w);
            o.z = pk_bf(c1.x, c1.y); o.w = pk_bf(c1.z, c1.w);
            *(uint4*)(hTf + ((((size_t)(b * NH + hd) * 64 + nb * 2 + p) * 4 + ct) * 512) + lane * 8) = o;
        }

        // ei/ej partial sums (canonical reads)
        float a1v[4], a2v[4];
        #pragma unroll
        for (int r = 0; r < 4; ++r) {
            const int d = ct * 16 + 4 * q + r;
            a1v[r] = a[d] * LOG2E;
            a2v[r] = a[64 + d] * LOG2E;
        }
        #pragma unroll
        for (int nt = 0; nt < 4; ++nt)
            #pragma unroll
            for (int r = 0; r < 4; ++r) {
                const float v = cs[hd][nt][4 * q + r][ln15];
                eip[nt] += v * a1v[r];
                ejq[nt] += v * a2v[r];
            }
    }
    #pragma unroll
    for (int nt = 0; nt < 4; ++nt) {
        eip[nt] += __shfl_xor(eip[nt], 16);
        eip[nt] += __shfl_xor(eip[nt], 32);
        ejq[nt] += __shfl_xor(ejq[nt], 16);
        ejq[nt] += __shfl_xor(ejq[nt], 32);
    }
    if (lane < 16) {
        const size_t bhd = (size_t)(b * NH + hd) * NN;
        #pragma unroll
        for (int nt = 0; nt < 4; ++nt) {
            const size_t idx = bhd + n0 + nt * 16 + lane;
            Ea_g[idx] = fast_exp2(eip[nt]);
            Ga_g[idx] = fast_exp2(0.2f * eip[nt]);
            Fb_g[idx] = fast_exp2(ejq[nt]);
            Hb_g[idx] = fast_exp2(0.2f * ejq[nt]);
        }
    }
}

// grid (ib=64, js, b=4), block 256 (wave = head).
// exp-free inner loop: p = max(Ei*Fj, Gi*Hj)  [= exp2(lrelu-scaled e), exact identity],
// adjacency applied as packed bf16 AND-masks precomputed in the prologue.
// pmsk layout: per (row, t) 16 u32 half-masks (32 j x 16 bit). Row stride NJT*16+4.
template <int NJT>
__global__ __launch_bounds__(256, 3)
void k_attn(const int* __restrict__ adj, const u16* __restrict__ hTf,
            const float* __restrict__ Ea, const float* __restrict__ Ga,
            const float* __restrict__ Fb, const float* __restrict__ Hb,
            float* __restrict__ o_part, float* __restrict__ l_part) {
    const int ib = blockIdx.x, js = blockIdx.y, b = blockIdx.z;
    const int js_n = gridDim.y;
    const int tid = threadIdx.x, hd = tid >> 6, lane = tid & 63, ln15 = lane & 15, q = lane >> 4;
    const int q8 = q * 8;
    const int iA = ib * 32 + ln15;
    const int jt0 = js * NJT;

    __shared__ u32   pmsk[32][NJT * 16 + 4];   // 16 u32 per (row,t); stride%32=4 -> 2-way alias (free)
    __shared__ float fjs[NH][NJT * 32];
    __shared__ float hjs[NH][NJT * 32];

    // ---- prologue A: adj -> packed bf16 AND-masks (no shfl; direct b64 writes) ----
    {
        const int row = (hd << 3) + (lane >> 3);                   // 0..31, 8 rows per wave
        const int lk = lane & 7;
        const int* abase = adj + (size_t)(b * NN + ib * 32 + row) * NN + jt0 * 32 + lk * 4;
        #pragma unroll
        for (int jb = 0; jb < NJT; jb += 8) {
            int4 vv[8];
            #pragma unroll
            for (int u = 0; u < 8; ++u)
                vv[u] = *(const int4*)(abase + (jb + u) * 32);
            #pragma unroll
            for (int u = 0; u < 8; ++u) {
                uint2 wv;
                wv.x = (vv[u].x ? 0xFFFFu : 0u) | (vv[u].y ? 0xFFFF0000u : 0u);
                wv.y = (vv[u].z ? 0xFFFFu : 0u) | (vv[u].w ? 0xFFFF0000u : 0u);
                *(uint2*)&pmsk[row][(jb + u) * 16 + lk * 2] = wv;
            }
        }
    }
    const size_t bhd = (size_t)(b * NH + hd) * NN;
    // ---- prologue B: F/H j-factor slices -> LDS (per head) ----
    {
        const float* fsrc = Fb + bhd + jt0 * 32;
        const float* hsrc = Hb + bhd + jt0 * 32;
        #pragma unroll
        for (int u = 0; u < NJT / 8; ++u) {
            const int o4 = (u * 64 + lane) * 4;
            *(float4*)&fjs[hd][o4] = *(const float4*)(fsrc + o4);
            *(float4*)&hjs[hd][o4] = *(const float4*)(hsrc + o4);
        }
    }
    __syncthreads();

    int irow[4], icol[4];
    cd_probe(ln15, q, irow, icol);

    const float EiA = Ea[bhd + iA];
    const float GiA = Ga[bhd + iA];
    const float EiB = Ea[bhd + iA + 16];
    const float GiB = Ga[bhd + iA + 16];
    const u16*  hfp = hTf + (size_t)(b * NH + hd) * (64 * 2048) + (size_t)lane * 8;

    sh8 ones;
    #pragma unroll
    for (int ii = 0; ii < 8; ++ii) ones[ii] = (short)0x3F80;

    f32x4 acc[8] = {};
    f32x4 accl[2] = {};

    sh8 H[2][4];
    #pragma unroll
    for (int s = 0; s < 2; ++s)
        #pragma unroll
        for (int k = 0; k < 4; ++k)
            H[s][k] = *(const sh8*)(hfp + (size_t)(jt0 + s) * 2048 + k * 512);

    #pragma unroll
    for (int t = 0; t < NJT; ++t) {
        const uint4 mwA = *(const uint4*)&pmsk[ln15][t * 16 + q * 4];
        const uint4 mwB = *(const uint4*)&pmsk[ln15 + 16][t * 16 + q * 4];
        const float4 f0 = *(const float4*)&fjs[hd][t * 32 + q8];
        const float4 f1 = *(const float4*)&fjs[hd][t * 32 + q8 + 4];
        const float4 h0 = *(const float4*)&hjs[hd][t * 32 + q8];
        const float4 h1 = *(const float4*)&hjs[hd][t * 32 + q8 + 4];
        const float pf[8] = { f0.x, f0.y, f0.z, f0.w, f1.x, f1.y, f1.z, f1.w };
        const float ph[8] = { h0.x, h0.y, h0.z, h0.w, h1.x, h1.y, h1.z, h1.w };
        const u32 mA[4] = { mwA.x, mwA.y, mwA.z, mwA.w };
        const u32 mB[4] = { mwB.x, mwB.y, mwB.z, mwB.w };

        uint4 uA, uB;
        u32 wA[4], wB[4];
        #pragma unroll
        for (int p = 0; p < 4; ++p) {
            const float a0 = fmaxf(EiA * pf[2 * p], GiA * ph[2 * p]);
            const float a1 = fmaxf(EiA * pf[2 * p + 1], GiA * ph[2 * p + 1]);
            wA[p] = cvt_pk(a0, a1) & mA[p];
            const float b0 = fmaxf(EiB * pf[2 * p], GiB * ph[2 * p]);
            const float b1 = fmaxf(EiB * pf[2 * p + 1], GiB * ph[2 * p + 1]);
            wB[p] = cvt_pk(b0, b1) & mB[p];
        }
        uA.x = wA[0]; uA.y = wA[1]; uA.z = wA[2]; uA.w = wA[3];
        uB.x = wB[0]; uB.y = wB[1]; uB.z = wB[2]; uB.w = wB[3];
        const sh8 av = __builtin_bit_cast(sh8, uA);
        const sh8 bv = __builtin_bit_cast(sh8, uB);

        acc[0] = __builtin_amdgcn_mfma_f32_16x16x32_bf16(av, H[t & 1][0], acc[0], 0, 0, 0);
        acc[1] = __builtin_amdgcn_mfma_f32_16x16x32_bf16(av, H[t & 1][1], acc[1], 0, 0, 0);
        acc[2] = __builtin_amdgcn_mfma_f32_16x16x32_bf16(av, H[t & 1][2], acc[2], 0, 0, 0);
        acc[3] = __builtin_amdgcn_mfma_f32_16x16x32_bf16(av, H[t & 1][3], acc[3], 0, 0, 0);
        accl[0] = __builtin_amdgcn_mfma_f32_16x16x32_bf16(av, ones, accl[0], 0, 0, 0);
        acc[4] = __builtin_amdgcn_mfma_f32_16x16x32_bf16(bv, H[t & 1][0], acc[4], 0, 0, 0);
        acc[5] = __builtin_amdgcn_mfma_f32_16x16x32_bf16(bv, H[t & 1][1], acc[5], 0, 0, 0);
        acc[6] = __builtin_amdgcn_mfma_f32_16x16x32_bf16(bv, H[t & 1][2], acc[6], 0, 0, 0);
        acc[7] = __builtin_amdgcn_mfma_f32_16x16x32_bf16(bv, H[t & 1][3], acc[7], 0, 0, 0);
        accl[1] = __builtin_amdgcn_mfma_f32_16x16x32_bf16(bv, ones, accl[1], 0, 0, 0);

        if (t + 2 < NJT) {
            #pragma unroll
            for (int k = 0; k < 4; ++k)
                H[t & 1][k] = *(const sh8*)(hfp + (size_t)(jt0 + t + 2) * 2048 + k * 512);
        }
    }

    const size_t pbA = (((size_t)b * 128 + ib * 2 + 0) * js_n + js) * NH + hd;
    const size_t pbB = (((size_t)b * 128 + ib * 2 + 1) * js_n + js) * NH + hd;
    #pragma unroll
    for (int r = 0; r < 4; ++r) {
        l_part[pbA * 16 + irow[r]] = accl[0][r];
        l_part[pbB * 16 + irow[r]] = accl[1][r];
    }
    float* opA = o_part + pbA * 1024;
    float* opB = o_part + pbB * 1024;
    #pragma unroll
    for (int dt = 0; dt < 4; ++dt)
        #pragma unroll
        for (int r = 0; r < 4; ++r) {
            opA[(size_t)irow[r] * 64 + dt * 16 + icol[r]] = acc[dt][r];
            opB[(size_t)irow[r] * 64 + dt * 16 + icol[r]] = acc[4 + dt][r];
        }
}

// accumulate-form combine (register-light)
template <int JS>
__global__ __launch_bounds__(256)
void k_combine(const float* __restrict__ o_part, const float* __restrict__ l_part,
               float* __restrict__ out) {
    const int ib = blockIdx.x, b = blockIdx.y;
    const int tid = threadIdx.x;
    const int i = tid >> 4, d4 = (tid & 15) * 4;
    float4 sacc = {0.f, 0.f, 0.f, 0.f};
    #pragma unroll
    for (int h = 0; h < NH; ++h) {
        float l = 0.f;
        float4 oh = {0.f, 0.f, 0.f, 0.f};
        #pragma unroll
        for (int js = 0; js < JS; ++js) {
            const size_t pbase = (((size_t)b * 128 + ib) * JS + js) * NH + h;
            l += l_part[pbase * 16 + i];
            const float4 ov = *(const float4*)(o_part + pbase * 1024 + (size_t)i * 64 + d4);
            oh.x += ov.x; oh.y += ov.y; oh.z += ov.z; oh.w += ov.w;
        }
        const float inv = 0.25f / l;
        sacc.x += oh.x * inv; sacc.y += oh.y * inv;
        sacc.z += oh.z * inv; sacc.w += oh.w * inv;
    }
    *(float4*)(out + ((size_t)(b * NN) + ib * 16 + i) * DD + d4) = sacc;
}

extern "C" void kernel_launch(void* const* d_in, const int* in_sizes, int n_in,
                              void* d_out, int out_size, void* d_ws, size_t ws_size,
                              hipStream_t stream) {
    const float* x = nullptr; const int* adj = nullptr;
    const float* W = nullptr; const float* a = nullptr;
    for (int i = 0; i < n_in; ++i) {
        switch (in_sizes[i]) {
            case NB * NN * FIN:  x   = (const float*)d_in[i]; break;
            case NB * NN * NN:   adj = (const int*)d_in[i];   break;
            case FIN * 256:      W   = (const float*)d_in[i]; break;
            case 2 * DD:         a   = (const float*)d_in[i]; break;
            default: break;
        }
    }
    if (!x)   x   = (const float*)d_in[0];
    if (!adj) adj = (const int*)d_in[1];
    if (!W)   W   = (const float*)d_in[2];
    if (!a)   a   = (const float*)d_in[3];
    float* out = (float*)d_out;

    char* ws = (char*)d_ws;
    u16*   WT  = (u16*)(ws);
    float* Ea  = (float*)(ws + 65536);
    float* Ga  = (float*)(ws + 196608);
    float* Fb  = (float*)(ws + 327680);
    float* Hb  = (float*)(ws + 458752);
    u16*   hTf = (u16*)(ws + 589824);
    float* l_p = (float*)(ws + 4784128);
    float* o_p = (float*)(ws + 5308416);

    const size_t need4 = 5308416 + (size_t)4 * 8388608;
    const int js_n = (ws_size >= need4) ? 4 : 2;   // harness ws = 256 MiB -> always 4

    k_prep<<<dim3(32), dim3(256), 0, stream>>>(W, WT);
    k_gemm_h<<<dim3(32, NB), dim3(256), 0, stream>>>(x, WT, a, hTf, Ea, Ga, Fb, Hb);
    if (js_n == 4)
        k_attn<16><<<dim3(64, 4, NB), dim3(256), 0, stream>>>(adj, hTf, Ea, Ga, Fb, Hb, o_p, l_p);
    else
        k_attn<32><<<dim3(64, 2, NB), dim3(256), 0, stream>>>(adj, hTf, Ea, Ga, Fb, Hb, o_p, l_p);
    if (js_n == 4)      k_combine<4><<<dim3(128, NB), dim3(256), 0, stream>>>(o_p, l_p, out);
    else                k_combine<2><<<dim3(128, NB), dim3(256), 0, stream>>>(o_p, l_p, out);
}

// Round 8
// 132.344 us; speedup vs baseline: 1.0296x; 1.0173x over previous
//
#include <hip/hip_runtime.h>

#define NN 2048
#define NH 4
#define DD 64
#define FIN 128
#define NB 4
#define LOG2E 1.44269504f

typedef unsigned short u16;
typedef unsigned int u32;
typedef short sh8 __attribute__((ext_vector_type(8)));
typedef float f32x4 __attribute__((ext_vector_type(4)));

static __device__ __forceinline__ u16 f2bf(float f) {   // RNE
    u32 u = __builtin_bit_cast(u32, f);
    u += 0x7fffu + ((u >> 16) & 1u);
    return (u16)(u >> 16);
}
static __device__ __forceinline__ u32 pk_bf(float a, float b) {
    u32 ua = __builtin_bit_cast(u32, a) + 0x8000u;
    u32 ub = __builtin_bit_cast(u32, b) + 0x8000u;
    return __builtin_amdgcn_perm(ub, ua, 0x07060302u);
}
// gfx950 packed f32->bf16 convert (RNE). Low word = a, high word = b.
static __device__ __forceinline__ u32 cvt_pk(float a, float b) {
    u32 r;
    asm("v_cvt_pk_bf16_f32 %0, %1, %2" : "=v"(r) : "v"(a), "v"(b));
    return r;
}
static __device__ __forceinline__ float fast_exp2(float x) {
    float r;
    asm("v_exp_f32 %0, %1" : "=v"(r) : "v"(x));
    return r;
}

// ---- runtime C/D layout probe (load-bearing since R4) ----
static __device__ __forceinline__ void cd_probe(int ln15, int q, int* irow, int* icol) {
    sh8 pa, pb, qa, qb;
    #pragma unroll
    for (int ii = 0; ii < 8; ++ii) {
        pa[ii] = (short)f2bf((float)ln15);   // A[m][k] = m
        pb[ii] = 0;
        qa[ii] = 0;
        qb[ii] = (short)f2bf((float)ln15);   // B[k][n] = n
    }
    if (q == 0) { pb[0] = (short)f2bf(1.0f); qa[0] = (short)f2bf(1.0f); }
    f32x4 z = {};
    f32x4 prow = __builtin_amdgcn_mfma_f32_16x16x32_bf16(pa, pb, z, 0, 0, 0);
    f32x4 pcol = __builtin_amdgcn_mfma_f32_16x16x32_bf16(qa, qb, z, 0, 0, 0);
    #pragma unroll
    for (int r = 0; r < 4; ++r) {
        irow[r] = (int)(prow[r] + 0.5f);
        icol[r] = (int)(pcol[r] + 0.5f);
    }
}

// ws layout (bytes):
//   WT   [256][128] bf16 @ 0        : 65536
//   Ea   [B][H][N] f32  @ 65536     : 131072   exp2(l2e*ei)
//   Ga   [B][H][N] f32  @ 196608    : 131072   exp2(0.2*l2e*ei)
//   Fb   [B][H][N] f32  @ 327680    : 131072   exp2(l2e*ej)
//   Hb   [B][H][N] f32  @ 458752    : 131072   exp2(0.2*l2e*ej)
//   hTf  fragment-major @ 589824    : 4194304  ([b][hd][jt64][dt4][lane64][8] bf16)
//   l_p  @ 4784128 : 131072*js  (js<=4)
//   o_p  @ 5308416 : 8388608*js (js<=4)

// W -> WT (transposed bf16). 32 blocks; adj packing lives in k_attn's prologue.
__global__ __launch_bounds__(256)
void k_prep(const float* __restrict__ W, u16* __restrict__ WT) {
    const int bt  = blockIdx.x;          // 0..31
    const int kt  = bt & 3;
    const int ct8 = bt >> 2;
    __shared__ float tile[32][33];
    const int tid = threadIdx.x;
    const int rr = tid >> 5, cc = tid & 31;
    #pragma unroll
    for (int i = 0; i < 4; ++i)
        tile[rr + 8 * i][cc] = W[(size_t)(kt * 32 + rr + 8 * i) * 256 + ct8 * 32 + cc];
    __syncthreads();
    #pragma unroll
    for (int i = 0; i < 4; ++i)
        WT[(size_t)(ct8 * 32 + rr + 8 * i) * FIN + kt * 32 + cc] = f2bf(tile[cc][rr + 8 * i]);
}

// h = x@W in MFMA fragment-major layout + exp-factor arrays. grid (nb=32, b=4), wave=head.
__global__ __launch_bounds__(256)
void k_gemm_h(const float* __restrict__ x, const u16* __restrict__ WT,
              const float* __restrict__ a,
              u16* __restrict__ hTf, float* __restrict__ Ea_g, float* __restrict__ Ga_g,
              float* __restrict__ Fb_g, float* __restrict__ Hb_g) {
    const int nb = blockIdx.x, b = blockIdx.y;
    const int tid = threadIdx.x, hd = tid >> 6, lane = tid & 63, ln15 = lane & 15, q = lane >> 4;
    const int q8 = q * 8;
    const int n0 = nb * 64;

    __shared__ u16 xs[64][136];
    __shared__ float cs[NH][4][16][20];   // [hd][nt][row][col+pad], reused per ct (same-wave)
    {
        const int col = (tid & 31) * 4;
        const int r0  = tid >> 5;
        #pragma unroll
        for (int rr = 0; rr < 8; ++rr) {
            const int row = r0 + rr * 8;
            const float4 v = *(const float4*)(x + ((size_t)(b * NN + n0 + row)) * FIN + col);
            *(u32*)&xs[row][col]     = pk_bf(v.x, v.y);
            *(u32*)&xs[row][col + 2] = pk_bf(v.z, v.w);
        }
    }
    __syncthreads();

    int irow[4], icol[4];
    cd_probe(ln15, q, irow, icol);

    f32x4 acc[4][4] = {};                // [ct][nt]
    #pragma unroll
    for (int ks = 0; ks < 4; ++ks) {
        sh8 af[4], bfr[4];
        #pragma unroll
        for (int ct = 0; ct < 4; ++ct)
            af[ct] = *(const sh8*)(WT + (size_t)(hd * 64 + ct * 16 + ln15) * FIN + ks * 32 + q8);
        #pragma unroll
        for (int nt = 0; nt < 4; ++nt)
            bfr[nt] = *(const sh8*)&xs[nt * 16 + ln15][ks * 32 + q8];
        #pragma unroll
        for (int ct = 0; ct < 4; ++ct)
            #pragma unroll
            for (int nt = 0; nt < 4; ++nt)
                acc[ct][nt] = __builtin_amdgcn_mfma_f32_16x16x32_bf16(af[ct], bfr[nt], acc[ct][nt], 0, 0, 0);
    }

    float eip[4] = {}, ejq[4] = {};
    #pragma unroll
    for (int ct = 0; ct < 4; ++ct) {
        // canonicalize this ct through LDS (same-wave: no barrier needed)
        #pragma unroll
        for (int nt = 0; nt < 4; ++nt)
            #pragma unroll
            for (int r = 0; r < 4; ++r)
                cs[hd][nt][irow[r]][icol[r]] = acc[ct][nt][r];

        // fragment-major hTf write: lane (ln15,q) holds d=ct*16+ln15, j=n0+p*32+q*8+i
        #pragma unroll
        for (int p = 0; p < 2; ++p) {
            const float4 c0 = *(const float4*)&cs[hd][2 * p + (q >> 1)][ln15][(q & 1) * 8];
            const float4 c1 = *(const float4*)&cs[hd][2 * p + (q >> 1)][ln15][(q & 1) * 8 + 4];
            uint4 o;
            o.x = pk_bf(c0.x, c0.y); o.y = pk_bf(c0.z, c0.w);
            o.z = pk_bf(c1.x, c1.y); o.w = pk_bf(c1.z, c1.w);
            *(uint4*)(hTf + ((((size_t)(b * NH + hd) * 64 + nb * 2 + p) * 4 + ct) * 512) + lane * 8) = o;
        }

        // ei/ej partial sums (canonical reads)
        float a1v[4], a2v[4];
        #pragma unroll
        for (int r = 0; r < 4; ++r) {
            const int d = ct * 16 + 4 * q + r;
            a1v[r] = a[d] * LOG2E;
            a2v[r] = a[64 + d] * LOG2E;
        }
        #pragma unroll
        for (int nt = 0; nt < 4; ++nt)
            #pragma unroll
            for (int r = 0; r < 4; ++r) {
                const float v = cs[hd][nt][4 * q + r][ln15];
                eip[nt] += v * a1v[r];
                ejq[nt] += v * a2v[r];
            }
    }
    #pragma unroll
    for (int nt = 0; nt < 4; ++nt) {
        eip[nt] += __shfl_xor(eip[nt], 16);
        eip[nt] += __shfl_xor(eip[nt], 32);
        ejq[nt] += __shfl_xor(ejq[nt], 16);
        ejq[nt] += __shfl_xor(ejq[nt], 32);
    }
    if (lane < 16) {
        const size_t bhd = (size_t)(b * NH + hd) * NN;
        #pragma unroll
        for (int nt = 0; nt < 4; ++nt) {
            const size_t idx = bhd + n0 + nt * 16 + lane;
            Ea_g[idx] = fast_exp2(eip[nt]);
            Ga_g[idx] = fast_exp2(0.2f * eip[nt]);
            Fb_g[idx] = fast_exp2(ejq[nt]);
            Hb_g[idx] = fast_exp2(0.2f * ejq[nt]);
        }
    }
}

// grid (ib=64, js, b=4), block 256 (wave = head).
// exp-free inner loop: p = max(Ei*Fj, Gi*Hj)  [exact identity with exp2-monotone lrelu],
// adjacency as u32 bitmask in LDS (4.2 KB), expanded to 16-bit AND-masks in VALU.
template <int NJT>
__global__ __launch_bounds__(256, 4)
void k_attn(const int* __restrict__ adj, const u16* __restrict__ hTf,
            const float* __restrict__ Ea, const float* __restrict__ Ga,
            const float* __restrict__ Fb, const float* __restrict__ Hb,
            float* __restrict__ o_part, float* __restrict__ l_part) {
    const int ib = blockIdx.x, js = blockIdx.y, b = blockIdx.z;
    const int js_n = gridDim.y;
    const int tid = threadIdx.x, hd = tid >> 6, lane = tid & 63, ln15 = lane & 15, q = lane >> 4;
    const int q8 = q * 8;
    const int iA = ib * 32 + ln15;
    const int jt0 = js * NJT;

    __shared__ u32   mlds[32][NJT + 1];     // u32 bitmask per (row, t); odd stride
    __shared__ float fjs[NH][NJT * 32];
    __shared__ float hjs[NH][NJT * 32];

    // ---- prologue A: adj -> bitmask in LDS (nibble + shfl-OR, 8-deep load batches) ----
    {
        const int row = (hd << 3) + (lane >> 3);                   // 0..31, 8 rows per wave
        const int lk = lane & 7;
        const int* abase = adj + (size_t)(b * NN + ib * 32 + row) * NN + jt0 * 32 + lk * 4;
        #pragma unroll
        for (int jb = 0; jb < NJT; jb += 8) {
            int4 vv[8];
            #pragma unroll
            for (int u = 0; u < 8; ++u)
                vv[u] = *(const int4*)(abase + (jb + u) * 32);
            #pragma unroll
            for (int u = 0; u < 8; ++u) {
                u32 nib = (vv[u].x ? 1u : 0u) | (vv[u].y ? 2u : 0u) |
                          (vv[u].z ? 4u : 0u) | (vv[u].w ? 8u : 0u);
                u32 w = nib << (4 * lk);
                w |= __shfl_xor(w, 1);
                w |= __shfl_xor(w, 2);
                w |= __shfl_xor(w, 4);
                if (lk == 0) mlds[row][jb + u] = w;
            }
        }
    }
    const size_t bhd = (size_t)(b * NH + hd) * NN;
    // ---- prologue B: F/H j-factor slices -> LDS (per head) ----
    {
        const float* fsrc = Fb + bhd + jt0 * 32;
        const float* hsrc = Hb + bhd + jt0 * 32;
        #pragma unroll
        for (int u = 0; u < NJT / 8; ++u) {
            const int o4 = (u * 64 + lane) * 4;
            *(float4*)&fjs[hd][o4] = *(const float4*)(fsrc + o4);
            *(float4*)&hjs[hd][o4] = *(const float4*)(hsrc + o4);
        }
    }
    __syncthreads();

    int irow[4], icol[4];
    cd_probe(ln15, q, irow, icol);

    const float EiA = Ea[bhd + iA];
    const float GiA = Ga[bhd + iA];
    const float EiB = Ea[bhd + iA + 16];
    const float GiB = Ga[bhd + iA + 16];
    const u16*  hfp = hTf + (size_t)(b * NH + hd) * (64 * 2048) + (size_t)lane * 8;

    sh8 ones;
    #pragma unroll
    for (int ii = 0; ii < 8; ++ii) ones[ii] = (short)0x3F80;

    f32x4 acc[8] = {};
    f32x4 accl[2] = {};

    sh8 H[2][4];
    #pragma unroll
    for (int s = 0; s < 2; ++s)
        #pragma unroll
        for (int k = 0; k < 4; ++k)
            H[s][k] = *(const sh8*)(hfp + (size_t)(jt0 + s) * 2048 + k * 512);

    #pragma unroll
    for (int t = 0; t < NJT; ++t) {
        const u32 mqA = mlds[ln15][t] >> q8;        // 8 bits for this lane's j-group
        const u32 mqB = mlds[ln15 + 16][t] >> q8;
        const float4 f0 = *(const float4*)&fjs[hd][t * 32 + q8];
        const float4 f1 = *(const float4*)&fjs[hd][t * 32 + q8 + 4];
        const float4 h0 = *(const float4*)&hjs[hd][t * 32 + q8];
        const float4 h1 = *(const float4*)&hjs[hd][t * 32 + q8 + 4];
        const float pf[8] = { f0.x, f0.y, f0.z, f0.w, f1.x, f1.y, f1.z, f1.w };
        const float ph[8] = { h0.x, h0.y, h0.z, h0.w, h1.x, h1.y, h1.z, h1.w };

        uint4 uA, uB;
        u32 wA[4], wB[4];
        #pragma unroll
        for (int p = 0; p < 4; ++p) {
            // expand 2 adjacency bits -> 2x16-bit AND-mask (0 - bit = 0x0000 / 0xFFFF...)
            const u32 mA32 = ((0u - ((mqA >> (2 * p)) & 1u)) & 0xFFFFu) |
                             ((0u - ((mqA >> (2 * p + 1)) & 1u)) << 16);
            const u32 mB32 = ((0u - ((mqB >> (2 * p)) & 1u)) & 0xFFFFu) |
                             ((0u - ((mqB >> (2 * p + 1)) & 1u)) << 16);
            const float a0 = fmaxf(EiA * pf[2 * p], GiA * ph[2 * p]);
            const float a1 = fmaxf(EiA * pf[2 * p + 1], GiA * ph[2 * p + 1]);
            wA[p] = cvt_pk(a0, a1) & mA32;
            const float b0 = fmaxf(EiB * pf[2 * p], GiB * ph[2 * p]);
            const float b1 = fmaxf(EiB * pf[2 * p + 1], GiB * ph[2 * p + 1]);
            wB[p] = cvt_pk(b0, b1) & mB32;
        }
        uA.x = wA[0]; uA.y = wA[1]; uA.z = wA[2]; uA.w = wA[3];
        uB.x = wB[0]; uB.y = wB[1]; uB.z = wB[2]; uB.w = wB[3];
        const sh8 av = __builtin_bit_cast(sh8, uA);
        const sh8 bv = __builtin_bit_cast(sh8, uB);

        acc[0] = __builtin_amdgcn_mfma_f32_16x16x32_bf16(av, H[t & 1][0], acc[0], 0, 0, 0);
        acc[1] = __builtin_amdgcn_mfma_f32_16x16x32_bf16(av, H[t & 1][1], acc[1], 0, 0, 0);
        acc[2] = __builtin_amdgcn_mfma_f32_16x16x32_bf16(av, H[t & 1][2], acc[2], 0, 0, 0);
        acc[3] = __builtin_amdgcn_mfma_f32_16x16x32_bf16(av, H[t & 1][3], acc[3], 0, 0, 0);
        accl[0] = __builtin_amdgcn_mfma_f32_16x16x32_bf16(av, ones, accl[0], 0, 0, 0);
        acc[4] = __builtin_amdgcn_mfma_f32_16x16x32_bf16(bv, H[t & 1][0], acc[4], 0, 0, 0);
        acc[5] = __builtin_amdgcn_mfma_f32_16x16x32_bf16(bv, H[t & 1][1], acc[5], 0, 0, 0);
        acc[6] = __builtin_amdgcn_mfma_f32_16x16x32_bf16(bv, H[t & 1][2], acc[6], 0, 0, 0);
        acc[7] = __builtin_amdgcn_mfma_f32_16x16x32_bf16(bv, H[t & 1][3], acc[7], 0, 0, 0);
        accl[1] = __builtin_amdgcn_mfma_f32_16x16x32_bf16(bv, ones, accl[1], 0, 0, 0);

        if (t + 2 < NJT) {
            #pragma unroll
            for (int k = 0; k < 4; ++k)
                H[t & 1][k] = *(const sh8*)(hfp + (size_t)(jt0 + t + 2) * 2048 + k * 512);
        }
    }

    const size_t pbA = (((size_t)b * 128 + ib * 2 + 0) * js_n + js) * NH + hd;
    const size_t pbB = (((size_t)b * 128 + ib * 2 + 1) * js_n + js) * NH + hd;
    #pragma unroll
    for (int r = 0; r < 4; ++r) {
        l_part[pbA * 16 + irow[r]] = accl[0][r];
        l_part[pbB * 16 + irow[r]] = accl[1][r];
    }
    float* opA = o_part + pbA * 1024;
    float* opB = o_part + pbB * 1024;
    #pragma unroll
    for (int dt = 0; dt < 4; ++dt)
        #pragma unroll
        for (int r = 0; r < 4; ++r) {
            opA[(size_t)irow[r] * 64 + dt * 16 + icol[r]] = acc[dt][r];
            opB[(size_t)irow[r] * 64 + dt * 16 + icol[r]] = acc[4 + dt][r];
        }
}

// accumulate-form combine (register-light)
template <int JS>
__global__ __launch_bounds__(256)
void k_combine(const float* __restrict__ o_part, const float* __restrict__ l_part,
               float* __restrict__ out) {
    const int ib = blockIdx.x, b = blockIdx.y;
    const int tid = threadIdx.x;
    const int i = tid >> 4, d4 = (tid & 15) * 4;
    float4 sacc = {0.f, 0.f, 0.f, 0.f};
    #pragma unroll
    for (int h = 0; h < NH; ++h) {
        float l = 0.f;
        float4 oh = {0.f, 0.f, 0.f, 0.f};
        #pragma unroll
        for (int js = 0; js < JS; ++js) {
            const size_t pbase = (((size_t)b * 128 + ib) * JS + js) * NH + h;
            l += l_part[pbase * 16 + i];
            const float4 ov = *(const float4*)(o_part + pbase * 1024 + (size_t)i * 64 + d4);
            oh.x += ov.x; oh.y += ov.y; oh.z += ov.z; oh.w += ov.w;
        }
        const float inv = 0.25f / l;
        sacc.x += oh.x * inv; sacc.y += oh.y * inv;
        sacc.z += oh.z * inv; sacc.w += oh.w * inv;
    }
    *(float4*)(out + ((size_t)(b * NN) + ib * 16 + i) * DD + d4) = sacc;
}

extern "C" void kernel_launch(void* const* d_in, const int* in_sizes, int n_in,
                              void* d_out, int out_size, void* d_ws, size_t ws_size,
                              hipStream_t stream) {
    const float* x = nullptr; const int* adj = nullptr;
    const float* W = nullptr; const float* a = nullptr;
    for (int i = 0; i < n_in; ++i) {
        switch (in_sizes[i]) {
            case NB * NN * FIN:  x   = (const float*)d_in[i]; break;
            case NB * NN * NN:   adj = (const int*)d_in[i];   break;
            case FIN * 256:      W   = (const float*)d_in[i]; break;
            case 2 * DD:         a   = (const float*)d_in[i]; break;
            default: break;
        }
    }
    if (!x)   x   = (const float*)d_in[0];
    if (!adj) adj = (const int*)d_in[1];
    if (!W)   W   = (const float*)d_in[2];
    if (!a)   a   = (const float*)d_in[3];
    float* out = (float*)d_out;

    char* ws = (char*)d_ws;
    u16*   WT  = (u16*)(ws);
    float* Ea  = (float*)(ws + 65536);
    float* Ga  = (float*)(ws + 196608);
    float* Fb  = (float*)(ws + 327680);
    float* Hb  = (float*)(ws + 458752);
    u16*   hTf = (u16*)(ws + 589824);
    float* l_p = (float*)(ws + 4784128);
    float* o_p = (float*)(ws + 5308416);

    const size_t need2 = 5308416 + (size_t)2 * 8388608;
    const int js_n = (ws_size >= need2) ? 2 : 1;   // harness ws = 256 MiB -> always 2

    k_prep<<<dim3(32), dim3(256), 0, stream>>>(W, WT);
    k_gemm_h<<<dim3(32, NB), dim3(256), 0, stream>>>(x, WT, a, hTf, Ea, Ga, Fb, Hb);
    if (js_n == 2)
        k_attn<32><<<dim3(64, 2, NB), dim3(256), 0, stream>>>(adj, hTf, Ea, Ga, Fb, Hb, o_p, l_p);
    else
        k_attn<64><<<dim3(64, 1, NB), dim3(256), 0, stream>>>(adj, hTf, Ea, Ga, Fb, Hb, o_p, l_p);
    if (js_n == 2) k_combine<2><<<dim3(128, NB), dim3(256), 0, stream>>>(o_p, l_p, out);
    else           k_combine<1><<<dim3(128, NB), dim3(256), 0, stream>>>(o_p, l_p, out);
}